// Round 11
// baseline (372.140 us; speedup 1.0000x reference)
//
#include <hip/hip_runtime.h>
#include <math.h>

#define PI_F 3.14159265358979323846f
#define EPSF 1e-6f

// ---- complex helpers written as float2 vector ops (clang emits v_pk_* on gfx950) ----
__device__ inline float2 cscale(float2 a, float s) { return make_float2(a.x * s, a.y * s); }
__device__ inline float2 cmul(float2 a, float2 b) {
  return b * a.x + make_float2(-b.y, b.x) * a.y;
}
__device__ inline float2 cmulc(float2 x, float cr, float ci) {
  return x * cr + make_float2(-x.y, x.x) * ci;
}
template <int SIGN>
__device__ inline float2 cj(float2 t) {  // SIGN * i * t
  return (SIGN > 0) ? make_float2(-t.y, t.x) : make_float2(t.y, -t.x);
}

// fp16 complex storage (P patch buffer, zf spectrum buffer, cz transpose buffer)
typedef _Float16 half2v __attribute__((ext_vector_type(2)));
__device__ inline float2 h2f(half2v h) { return make_float2((float)h.x, (float)h.y); }
__device__ inline half2v f2h(float2 f) {
  half2v h; h.x = (_Float16)f.x; h.y = (_Float16)f.y; return h;
}

__device__ inline void twiddle(float ang, float* s, float* c) {
  __sincosf(ang, s, c);
}

// base-4 digit reversal (10-bit, N=1024 column passes)
__device__ inline int rev4_10(int r) {
  unsigned b = __brev((unsigned)r) >> 22;
  return (int)(((b & 0x2AAu) >> 1) | ((b & 0x155u) << 1));
}

// ---------------- radix-4 twiddle tables in LDS ----------------
template <int NB4MAX>
__device__ inline void fill_tw(float2* TW, int tid, int T) {
#pragma unroll
  for (int sz = 1; sz <= NB4MAX; sz <<= 2) {
    int base = (sz - 1) / 3;
    for (int k = tid; k < sz; k += T) {
      float ang = (PI_F * 0.5f) * (float)k / (float)sz;
      float s1, c1;
      twiddle(ang, &s1, &c1);
      float2 w1 = make_float2(c1, s1);
      float2 w2 = cmul(w1, w1);
      float2 w3 = cmul(w2, w1);
      int e = (base + k) * 3;
      TW[e] = w1; TW[e + 1] = w2; TW[e + 2] = w3;
    }
  }
}

template <int SIGN>
__device__ inline void ldtw(const float2* __restrict__ TW, int sz, int k,
                            float2* w1, float2* w2, float2* w3) {
  int e = ((sz - 1) / 3 + k) * 3;
  float2 a = TW[e], b = TW[e + 1], c = TW[e + 2];
  if (SIGN < 0) { a.y = -a.y; b.y = -b.y; c.y = -c.y; }
  *w1 = a; *w2 = b; *w3 = c;
}

// ---------------- fully-unrolled 16-pt FFT in registers (natural in/out) ----------------
template <int SIGN>
__device__ inline void fft16_reg(float2* v) {
  const float sg = (float)SIGN;
  const float C1 = 0.9238795325112867f, S1 = 0.3826834323650898f, R = 0.7071067811865476f;
  float2 g[16];
#pragma unroll
  for (int a0 = 0; a0 < 4; ++a0) {
    float2 x0 = v[a0], x1 = v[a0 + 4], x2 = v[a0 + 8], x3 = v[a0 + 12];
    float2 t0 = x0 + x2;
    float2 t1 = x0 - x2;
    float2 t2 = x1 + x3;
    float2 t3 = x1 - x3;
    float2 j3 = cj<SIGN>(t3);
    g[a0 * 4 + 0] = t0 + t2;
    g[a0 * 4 + 1] = t1 + j3;
    g[a0 * 4 + 2] = t0 - t2;
    g[a0 * 4 + 3] = t1 - j3;
  }
  g[5]  = cmulc(g[5],  C1, sg * S1);
  g[6]  = cmulc(g[6],  R,  sg * R);
  g[7]  = cmulc(g[7],  S1, sg * C1);
  g[9]  = cmulc(g[9],  R,  sg * R);
  g[10] = cj<SIGN>(g[10]);
  g[11] = cmulc(g[11], -R, sg * R);
  g[13] = cmulc(g[13], S1, sg * C1);
  g[14] = cmulc(g[14], -R, sg * R);
  g[15] = cmulc(g[15], -C1, -sg * S1);
#pragma unroll
  for (int k0 = 0; k0 < 4; ++k0) {
    float2 x0 = g[k0], x1 = g[4 + k0], x2 = g[8 + k0], x3 = g[12 + k0];
    float2 t0 = x0 + x2;
    float2 t1 = x0 - x2;
    float2 t2 = x1 + x3;
    float2 t3 = x1 - x3;
    float2 j3 = cj<SIGN>(t3);
    v[k0]      = t0 + t2;
    v[k0 + 4]  = t1 + j3;
    v[k0 + 8]  = t0 - t2;
    v[k0 + 12] = t1 - j3;
  }
}

// ---------------- Stockham radix-4 FFT in LDS (row passes) ----------------
template <int N, int T, int SIGN>
__device__ inline float2* fft4_lds(float2* bufA, float2* bufB, int tid,
                                   const float2* __restrict__ TW) {
  const int NB4 = N / 4;
  const int BPT = NB4 / T;
  const int STAGES = (N == 1024) ? 5 : 4;
  float2* src = bufA;
  float2* dst = bufB;
  for (int s = 0; s < STAGES; ++s) {
    const int m = 1 << (2 * s);
    const int l = NB4 >> (2 * s);
    __syncthreads();
#pragma unroll
    for (int u = 0; u < BPT; ++u) {
      int bf = tid + u * T;
      int k = bf & (m - 1);
      int j = bf >> (2 * s);
      float2 x0 = src[bf];
      float2 x1 = src[bf + NB4];
      float2 x2 = src[bf + 2 * NB4];
      float2 x3 = src[bf + 3 * NB4];
      float2 t0 = x0 + x2;
      float2 t1 = x0 - x2;
      float2 t2 = x1 + x3;
      float2 t3 = x1 - x3;
      float2 j3 = cj<SIGN>(t3);
      float2 y0 = t0 + t2;
      float2 y1 = t1 + j3;
      float2 y2 = t0 - t2;
      float2 y3 = t1 - j3;
      float2 w1, w2, w3;
      ldtw<SIGN>(TW, l, j, &w1, &w2, &w3);
      int o = ((bf - k) << 2) + k;
      dst[o] = y0;
      dst[o + m] = cmul(y1, w1);
      dst[o + 2 * m] = cmul(y2, w2);
      dst[o + 3 * m] = cmul(y3, w3);
    }
    float2* tmp = src; src = dst; dst = tmp;
  }
  __syncthreads();
  return src;
}

// ---------------- in-place multi-column radix-4 FFTs (1024-pt column passes) ----------------
template <int N, int CW, int T, int SIGN>
__device__ inline void dif4_mc(float2* A, int tid, const float2* __restrict__ TW) {
  const int NB4 = N / 4;
  const int LOG4 = (N == 1024) ? 5 : 4;
  const int ITER = (NB4 * CW) / T;
  const int BSTR = T / CW;
  int c = tid & (CW - 1);
  int bb = tid / CW;
  for (int s = 0; s < LOG4; ++s) {
    int q = NB4 >> (2 * s);
    __syncthreads();
#pragma unroll
    for (int u = 0; u < ITER; ++u) {
      int bf = bb + BSTR * u;
      int j = bf & (q - 1);
      int i0 = ((bf - j) << 2) + j;
      float2 x0 = A[(i0) * CW + c];
      float2 x1 = A[(i0 + q) * CW + c];
      float2 x2 = A[(i0 + 2 * q) * CW + c];
      float2 x3 = A[(i0 + 3 * q) * CW + c];
      float2 t0 = x0 + x2;
      float2 t1 = x0 - x2;
      float2 t2 = x1 + x3;
      float2 t3 = x1 - x3;
      float2 j3 = cj<SIGN>(t3);
      float2 y0 = t0 + t2;
      float2 y1 = t1 + j3;
      float2 y2 = t0 - t2;
      float2 y3 = t1 - j3;
      float2 w1, w2, w3;
      ldtw<SIGN>(TW, q, j, &w1, &w2, &w3);
      A[(i0) * CW + c] = y0;
      A[(i0 + q) * CW + c] = cmul(y1, w1);
      A[(i0 + 2 * q) * CW + c] = cmul(y2, w2);
      A[(i0 + 3 * q) * CW + c] = cmul(y3, w3);
    }
  }
  __syncthreads();
}

template <int N, int CW, int T, int SIGN>
__device__ inline void dit4_mc(float2* A, int tid, const float2* __restrict__ TW) {
  const int NB4 = N / 4;
  const int LOG4 = (N == 1024) ? 5 : 4;
  const int ITER = (NB4 * CW) / T;
  const int BSTR = T / CW;
  int c = tid & (CW - 1);
  int bb = tid / CW;
  for (int s = 0; s < LOG4; ++s) {
    int m = 1 << (2 * s);
    __syncthreads();
#pragma unroll
    for (int u = 0; u < ITER; ++u) {
      int bf = bb + BSTR * u;
      int k = bf & (m - 1);
      int i0 = ((bf - k) << 2) + k;
      float2 w1, w2, w3;
      ldtw<SIGN>(TW, m, k, &w1, &w2, &w3);
      float2 x0 = A[(i0) * CW + c];
      float2 x1 = cmul(A[(i0 + m) * CW + c], w1);
      float2 x2 = cmul(A[(i0 + 2 * m) * CW + c], w2);
      float2 x3 = cmul(A[(i0 + 3 * m) * CW + c], w3);
      float2 t0 = x0 + x2;
      float2 t1 = x0 - x2;
      float2 t2 = x1 + x3;
      float2 t3 = x1 - x3;
      float2 j3 = cj<SIGN>(t3);
      A[(i0) * CW + c] = t0 + t2;
      A[(i0 + m) * CW + c] = t1 + j3;
      A[(i0 + 2 * m) * CW + c] = t0 - t2;
      A[(i0 + 3 * m) * CW + c] = t1 - j3;
    }
  }
  __syncthreads();
}

// ---------------- 1024-point row passes ----------------

__global__ __launch_bounds__(256) void k_fft_rows_big(
    const float* __restrict__ re, const float* __restrict__ im,
    half2v* __restrict__ zf) {
  __shared__ float2 A[1024], Bb[1024];
  __shared__ float2 TW[341 * 3];
  long base = (long)blockIdx.x * 1024;
  int tid = threadIdx.x;
  fill_tw<256>(TW, tid, 256);
#pragma unroll
  for (int k = 0; k < 4; ++k) {
    int q = tid + k * 256;
    A[q] = make_float2(re[base + q], im[base + q]);
  }
  float2* res = fft4_lds<1024, 256, -1>(A, Bb, tid, TW);
#pragma unroll
  for (int k = 0; k < 4; ++k) {
    int q = tid + k * 256;
    zf[base + ((q + 512) & 1023)] = f2h(res[q]);
  }
}

// row IFFT of U fused with the final combine
__global__ __launch_bounds__(256) void k_ifft_rows_combine(
    const float2* __restrict__ U, const float* __restrict__ Ia,
    const float* __restrict__ Icr, const float* __restrict__ Ici,
    const float* __restrict__ lamb, const float* __restrict__ eta1,
    float* __restrict__ out, long out_elems) {
  __shared__ float2 A[1024], Bb[1024];
  __shared__ float2 TW[341 * 3];
  long base = (long)blockIdx.x * 1024;
  int tid = threadIdx.x;
  fill_tw<256>(TW, tid, 256);
#pragma unroll
  for (int k = 0; k < 4; ++k) {
    int q = tid + k * 256;
    A[q] = U[base + ((q + 512) & 1023)];
  }
  float2* res = fft4_lds<1024, 256, 1>(A, Bb, tid, TW);
  const float sc = 1.0f / 1024.0f;
  const long NTOT = 4L * 1024 * 1024;
  float e1 = eta1[0], lm = lamb[0];
  float c1 = 100.0f * e1 * lm;
  float c2 = 10.0f * e1;
#pragma unroll
  for (int k = 0; k < 4; ++k) {
    int q = tid + k * 256;
    long i = base + q;
    float2 w = cscale(res[q], sc);
    float cr = Icr[i], ci = Ici[i], a = Ia[i];
    float mag = sqrtf(cr * cr + ci * ci);
    float t = a / (mag + EPSF);
    float rx = cr * (1.0f - c1) + c1 * cr * t - c2 * w.x;
    float ry = ci * (1.0f - c1) + c1 * ci * t - c2 * w.y;
    if (i < out_elems) out[i] = sqrtf(rx * rx + ry * ry);
    if (NTOT + i < out_elems) out[NTOT + i] = rx;
    if (2 * NTOT + i < out_elems) out[2 * NTOT + i] = ry;
  }
}

// ---------------- 1024-point column passes (zf fp16; LDS compute fp32) ----------------

__global__ __launch_bounds__(256) void k_fft_cols_mc(half2v* __restrict__ zf) {
  __shared__ float2 A[8192];
  __shared__ float2 TW[341 * 3];
  int b = blockIdx.x >> 7;
  int c0 = (blockIdx.x & 127) * 8;
  long base = (long)b * 1048576 + c0;
  int tid = threadIdx.x;
  fill_tw<256>(TW, tid, 256);
#pragma unroll
  for (int u = 0; u < 32; ++u) {
    int v = tid + 256 * u;
    int r = v >> 3, c = v & 7;
    A[v] = h2f(zf[base + (long)r * 1024 + c]);
  }
  dif4_mc<1024, 8, 256, -1>(A, tid, TW);
#pragma unroll
  for (int u = 0; u < 32; ++u) {
    int v = tid + 256 * u;
    int r = v >> 3, c = v & 7;
    int i = rev4_10(r);
    zf[base + (long)((i + 512) & 1023) * 1024 + c] = f2h(A[v]);
  }
}

__global__ __launch_bounds__(256) void k_ifft_cols_mc(float2* __restrict__ U) {
  __shared__ float2 A[8192];
  __shared__ float2 TW[341 * 3];
  int b = blockIdx.x >> 7;
  int c0 = (blockIdx.x & 127) * 8;
  long base = (long)b * 1048576 + c0;
  int tid = threadIdx.x;
  fill_tw<256>(TW, tid, 256);
#pragma unroll
  for (int u = 0; u < 32; ++u) {
    int v = tid + 256 * u;
    int r = v >> 3, c = v & 7;
    int i = rev4_10(r);
    A[v] = U[base + (long)((i + 512) & 1023) * 1024 + c];
  }
  dit4_mc<1024, 8, 256, 1>(A, tid, TW);
  const float sc = 1.0f / 1024.0f;
#pragma unroll
  for (int u = 0; u < 32; ++u) {
    int v = tid + 256 * u;
    int r = v >> 3, c = v & 7;
    U[base + (long)r * 1024 + c] = cscale(A[v], sc);
  }
}

// ---------------- 256-point patch passes (P stored as fp16 complex) ----------------

__global__ __launch_bounds__(256) void k_patch_gather_irows(
    const half2v* __restrict__ zf, const int* __restrict__ masks,
    const float* __restrict__ ctf, half2v* __restrict__ P, int g0) {
  __shared__ float2 A[1024], Bb[1024];
  __shared__ float2 TW[85 * 3];
  int idx = blockIdx.x;  // li*64 + p4
  int li = idx >> 6;
  int sub = threadIdx.x >> 6;
  int p = ((idx & 63) << 2) + sub;
  int t = threadIdx.x & 63;
  int g = g0 + li;
  int l = g & 63, b = g >> 6;
  int br = masks[2 * l] - 1, bc = masks[2 * l + 1] - 1;
  int sp = (p + 128) & 255;
  long zbase = (long)b * (1024 * 1024) + (long)(br + sp) * 1024 + bc;
  const float* crow = ctf + sp * 256;
  float2* Ar = A + sub * 256;
  float2* Br = Bb + sub * 256;
  fill_tw<64>(TW, threadIdx.x, 256);
#pragma unroll
  for (int k = 0; k < 4; ++k) {
    int q = t + k * 64;
    int sq = (q + 128) & 255;
    float cv = crow[sq];
    float2 v = h2f(zf[zbase + sq]);
    Ar[q] = cscale(v, cv);
  }
  float2* res = fft4_lds<256, 64, 1>(Ar, Br, t, TW);
  const float sc = 1.0f / 256.0f;
  long pbase = ((long)li * 256 + p) * 256;
#pragma unroll
  for (int k = 0; k < 4; ++k) {
    int q = t + k * 64;
    P[pbase + q] = f2h(cscale(res[q], sc));
  }
}

// Register-resident 16x16 column IFFT -> phase replace -> column FFT.
// 1024 threads / 64-column slab: every global access is a 256B contiguous wave burst.
__global__ __launch_bounds__(1024) void k_patch_cz_reg(
    half2v* __restrict__ P, const float* __restrict__ Y, int g0) {
  __shared__ half2v TZ[16640];  // idx = (hi*16+c)*65 + lo, lo in [0,64)
  __shared__ float2 W[256];     // W[m] = exp(+2pi i m/256)
  int li = blockIdx.x >> 2;
  int q0 = (blockIdx.x & 3) * 64;
  int g = g0 + li;
  int tid = threadIdx.x;
  int lo = tid & 63;            // column within 64-col slab
  int hi = tid >> 6;            // FFT digit, [0,16)
  // prefetch Y (256B contiguous bursts; hides latency under phases 1-2)
  const float* Yg = Y + (long)g * 65536 + q0 + lo;
  float sY[16];
#pragma unroll
  for (int d = 0; d < 16; ++d) sY[d] = Yg[(long)(hi + 16 * d) * 256];
  if (tid < 256) {
    float ang = (2.0f * PI_F / 256.0f) * (float)tid;
    float sn, cs;
    twiddle(ang, &sn, &cs);
    W[tid] = make_float2(cs, sn);
  }
  long pcol = (long)li * 65536 + q0 + lo;
  float2 v[16];
#pragma unroll
  for (int a = 0; a < 16; ++a) v[a] = h2f(P[pcol + (long)(16 * a + hi) * 256]);
  fft16_reg<1>(v);
  __syncthreads();              // W ready
#pragma unroll
  for (int c = 1; c < 16; ++c) v[c] = cmul(v[c], W[hi * c]);
#pragma unroll
  for (int c = 0; c < 16; ++c) TZ[(hi * 16 + c) * 65 + lo] = f2h(v[c]);
  __syncthreads();
#pragma unroll
  for (int b = 0; b < 16; ++b) v[b] = h2f(TZ[(b * 16 + hi) * 65 + lo]);
  fft16_reg<1>(v);
  const float sc = 1.0f / 256.0f;
#pragma unroll
  for (int d = 0; d < 16; ++d) {
    float2 bz = cscale(v[d], sc);
    float s = sqrtf(sY[d]);
    float m2 = bz.x * bz.x + bz.y * bz.y;
    float inv = (m2 > 0.0f) ? rsqrtf(m2) : 0.0f;
    float px = (m2 > 0.0f) ? bz.x * inv : 1.0f;
    float py = bz.y * inv;
    v[d] = make_float2(bz.x - s * px, bz.y - s * py);
  }
  fft16_reg<-1>(v);
#pragma unroll
  for (int e = 1; e < 16; ++e) {
    float2 w = W[hi * e];
    v[e] = cmul(v[e], make_float2(w.x, -w.y));
  }
  __syncthreads();
#pragma unroll
  for (int e = 0; e < 16; ++e) TZ[(hi * 16 + e) * 65 + lo] = f2h(v[e]);
  __syncthreads();
#pragma unroll
  for (int c = 0; c < 16; ++c) v[c] = h2f(TZ[(c * 16 + hi) * 65 + lo]);
  fft16_reg<-1>(v);
#pragma unroll
  for (int f = 0; f < 16; ++f) {
    int row = (hi + 16 * f + 128) & 255;
    P[(long)li * 65536 + (long)row * 256 + q0 + lo] = f2h(v[f]);
  }
}

// (fallback only) row-FFT patches in place
__global__ __launch_bounds__(256) void k_patch_rows_store(
    half2v* __restrict__ P, const float* __restrict__ ctf) {
  __shared__ float2 A[1024], Bb[1024];
  __shared__ float2 TW[85 * 3];
  int idx = blockIdx.x;
  int li = idx >> 6;
  int sub = threadIdx.x >> 6;
  int p = ((idx & 63) << 2) + sub;
  int t = threadIdx.x & 63;
  long pbase = ((long)li * 256 + p) * 256;
  float2* Ar = A + sub * 256;
  float2* Br = Bb + sub * 256;
  fill_tw<64>(TW, threadIdx.x, 256);
#pragma unroll
  for (int k = 0; k < 4; ++k) {
    int q = t + k * 64;
    Ar[q] = h2f(P[pbase + q]);
  }
  float2* res = fft4_lds<256, 64, -1>(Ar, Br, t, TW);
  const float sc = 1.0f / 64.0f;
  const float* crow = ctf + p * 256;
#pragma unroll
  for (int k = 0; k < 4; ++k) {
    int q = t + k * 64;
    int qp = (q + 128) & 255;
    float cv = crow[qp] * sc;
    P[pbase + qp] = f2h(cscale(res[q], cv));
  }
}

// FULL mode: fused row-FFT + gather-accumulate.
__global__ __launch_bounds__(256) void k_patch_accum_fft(
    const half2v* __restrict__ P, const int* __restrict__ masks,
    const float* __restrict__ ctf, float2* __restrict__ U) {
  __shared__ float2 A[1024], Bb[1024];
  __shared__ float2 TW[85 * 3];
  __shared__ int cl_li[64], cl_dr[64], cl_bc[64];
  __shared__ int s_n;
  int r = blockIdx.x & 1023;
  int b = blockIdx.x >> 10;
  int tid = threadIdx.x;
  fill_tw<64>(TW, tid, 256);
  if (tid < 64) {
    int br = masks[2 * tid] - 1;
    int dr = r - br;
    bool cov = (unsigned)dr < 256u;
    unsigned long long m = __ballot(cov);
    if (cov) {
      int slot = __popcll(m & ((1ull << tid) - 1ull));
      cl_li[slot] = tid;
      cl_dr[slot] = dr;
      cl_bc[slot] = masks[2 * tid + 1] - 1;
    }
    if (tid == 0) s_n = (int)__popcll(m);
  }
  __syncthreads();
  int n = s_n;
  int sub = tid >> 6, t = tid & 63;
  float2 acc[4];
#pragma unroll
  for (int k = 0; k < 4; ++k) acc[k] = make_float2(0.0f, 0.0f);
  const float sc = 1.0f / 64.0f;
  for (int c0 = 0; c0 < n; c0 += 4) {
    int slot = c0 + sub;
    float2* Ar = A + sub * 256;
    float2* Br = Bb + sub * 256;
    if (slot < n) {
      long pbase = (((long)b * 64 + cl_li[slot]) * 256 + cl_dr[slot]) * 256;
#pragma unroll
      for (int k = 0; k < 4; ++k) Ar[t + 64 * k] = h2f(P[pbase + t + 64 * k]);
    } else {
#pragma unroll
      for (int k = 0; k < 4; ++k) Ar[t + 64 * k] = make_float2(0.0f, 0.0f);
    }
    fft4_lds<256, 64, -1>(Ar, Br, t, TW);
    int mm = (n - c0) < 4 ? (n - c0) : 4;
    for (int ss = 0; ss < mm; ++ss) {
      int dr2 = cl_dr[c0 + ss], bc2 = cl_bc[c0 + ss];
      const float* crow = ctf + dr2 * 256;
      const float2* resb = A + ss * 256;
#pragma unroll
      for (int k = 0; k < 4; ++k) {
        int dc = tid + 256 * k - bc2;
        if ((unsigned)dc < 256u) {
          float2 v = resb[(dc + 128) & 255];
          float cv = crow[dc] * sc;
          acc[k] = acc[k] + v * cv;
        }
      }
    }
    __syncthreads();
  }
  long ubase = (long)b * 1048576 + (long)r * 1024;
#pragma unroll
  for (int k = 0; k < 4; ++k) U[ubase + tid + 256 * k] = acc[k];
}

// (fallback only) plain gather-accumulate
__global__ __launch_bounds__(256) void k_patch_accum(
    const half2v* __restrict__ P, const int* __restrict__ masks,
    float2* __restrict__ U, int b_base, int l0, int nc, int accum, int g0) {
  __shared__ int sbr[64], sbc[64];
  int r = blockIdx.x & 1023;
  int b = b_base + (blockIdx.x >> 10);
  int tid = threadIdx.x;
  if (tid < nc) {
    sbr[tid] = masks[2 * (l0 + tid)] - 1;
    sbc[tid] = masks[2 * (l0 + tid) + 1] - 1;
  }
  __syncthreads();
  long ubase = (long)b * 1048576 + (long)r * 1024;
  long sbase = (long)(b * 64 + l0 - g0);
  float2 acc[4];
  if (accum) {
#pragma unroll
    for (int k = 0; k < 4; ++k) acc[k] = U[ubase + tid + 256 * k];
  } else {
#pragma unroll
    for (int k = 0; k < 4; ++k) acc[k] = make_float2(0.0f, 0.0f);
  }
  for (int li = 0; li < nc; ++li) {
    int dr = r - sbr[li];
    if ((unsigned)dr < 256u) {
      const half2v* prow = P + ((sbase + li) * 256 + dr) * 256;
      int bc = sbc[li];
#pragma unroll
      for (int k = 0; k < 4; ++k) {
        int dc = tid + 256 * k - bc;
        if ((unsigned)dc < 256u) {
          acc[k] = acc[k] + h2f(prow[dc]);
        }
      }
    }
  }
#pragma unroll
  for (int k = 0; k < 4; ++k) U[ubase + tid + 256 * k] = acc[k];
}

extern "C" void kernel_launch(void* const* d_in, const int* in_sizes, int n_in,
                              void* d_out, int out_size, void* d_ws, size_t ws_size,
                              hipStream_t stream) {
  (void)in_sizes; (void)n_in;
  const float* Ia   = (const float*)d_in[0];
  const float* Icr  = (const float*)d_in[1];
  const float* Ici  = (const float*)d_in[2];
  const float* Y    = (const float*)d_in[3];
  const int*   Masks = (const int*)d_in[4];
  const float* CTF  = (const float*)d_in[5];
  const float* lamb = (const float*)d_in[6];
  const float* eta1 = (const float*)d_in[7];
  float* out = (float*)d_out;

  const size_t MB32 = 32ull * 1024 * 1024;
  const size_t MB16 = 16ull * 1024 * 1024;
  const size_t PATCH_BYTES = 256 * 256 * sizeof(half2v);  // 256 KiB (fp16)
  const size_t P_FULL = 256ull * PATCH_BYTES;             // 64 MiB

  char* wsb = (char*)d_ws;

  // ---------- FULL mode: all 4 batches in one patch pipeline ----------
  if (ws_size >= MB32 + MB16 + P_FULL) {
    float2* U  = (float2*)wsb;
    half2v* zf = (half2v*)(wsb + MB32);
    half2v* P  = (half2v*)(wsb + MB32 + MB16);

    k_fft_rows_big<<<4096, 256, 0, stream>>>(Icr, Ici, zf);
    k_fft_cols_mc<<<512, 256, 0, stream>>>(zf);

    k_patch_gather_irows<<<256 * 64, 256, 0, stream>>>(zf, Masks, CTF, P, 0);
    k_patch_cz_reg<<<256 * 4, 1024, 0, stream>>>(P, Y, 0);
    k_patch_accum_fft<<<4096, 256, 0, stream>>>(P, Masks, CTF, U);

    k_ifft_cols_mc<<<512, 256, 0, stream>>>(U);
    k_ifft_rows_combine<<<4096, 256, 0, stream>>>(U, Ia, Icr, Ici, lamb, eta1, out,
                                                  (long)out_size);
    return;
  }

  // ---------- fallback: chunked pipeline ----------
  float2* U = (float2*)wsb;
  size_t used = MB32;
  if (used > ws_size) used = ws_size;

  half2v* zf;
  bool zf_in_ws = (ws_size >= MB32 + MB16 + PATCH_BYTES);
  bool zf_in_out = (!zf_in_ws) && ((size_t)out_size * sizeof(float) >= MB16);
  if (zf_in_ws) { zf = (half2v*)(wsb + used); used += MB16; }
  else if (zf_in_out) { zf = (half2v*)d_out; }
  else { zf = (half2v*)U; }

  size_t rem = (ws_size > used) ? (ws_size - used) : 0;
  long ncl = (long)(rem / PATCH_BYTES);
  int NC = (int)(ncl < 1 ? 1 : (ncl > 64 ? 64 : ncl));
  half2v* P = (half2v*)(wsb + ((rem >= PATCH_BYTES) ? used : 0));

  k_fft_rows_big<<<4096, 256, 0, stream>>>(Icr, Ici, zf);
  k_fft_cols_mc<<<512, 256, 0, stream>>>(zf);

  for (int b = 0; b < 4; ++b) {
    for (int l0 = 0; l0 < 64; l0 += NC) {
      int nc = (64 - l0) < NC ? (64 - l0) : NC;
      int g0 = b * 64 + l0;
      k_patch_gather_irows<<<nc * 64, 256, 0, stream>>>(zf, Masks, CTF, P, g0);
      k_patch_cz_reg<<<nc * 4, 1024, 0, stream>>>(P, Y, g0);
      k_patch_rows_store<<<nc * 64, 256, 0, stream>>>(P, CTF);
      k_patch_accum<<<1024, 256, 0, stream>>>(P, Masks, U, b, l0, nc, l0 > 0 ? 1 : 0, g0);
    }
  }

  k_ifft_cols_mc<<<512, 256, 0, stream>>>(U);
  k_ifft_rows_combine<<<4096, 256, 0, stream>>>(U, Ia, Icr, Ici, lamb, eta1, out,
                                                (long)out_size);
}

// Round 12
// 357.410 us; speedup vs baseline: 1.0412x; 1.0412x over previous
//
#include <hip/hip_runtime.h>
#include <math.h>

#define PI_F 3.14159265358979323846f
#define EPSF 1e-6f

// ---- complex helpers written as float2 vector ops (clang emits v_pk_* on gfx950) ----
__device__ inline float2 cscale(float2 a, float s) { return make_float2(a.x * s, a.y * s); }
__device__ inline float2 cmul(float2 a, float2 b) {
  return b * a.x + make_float2(-b.y, b.x) * a.y;
}
__device__ inline float2 cmulc(float2 x, float cr, float ci) {
  return x * cr + make_float2(-x.y, x.x) * ci;
}
template <int SIGN>
__device__ inline float2 cj(float2 t) {  // SIGN * i * t
  return (SIGN > 0) ? make_float2(-t.y, t.x) : make_float2(t.y, -t.x);
}

// fp16 complex storage (P patch buffer, zf spectrum buffer, transpose buffers)
typedef _Float16 half2v __attribute__((ext_vector_type(2)));
__device__ inline float2 h2f(half2v h) { return make_float2((float)h.x, (float)h.y); }
__device__ inline half2v f2h(float2 f) {
  half2v h; h.x = (_Float16)f.x; h.y = (_Float16)f.y; return h;
}

__device__ inline void twiddle(float ang, float* s, float* c) {
  __sincosf(ang, s, c);
}

// base-4 digit reversal (10-bit, N=1024 column passes)
__device__ inline int rev4_10(int r) {
  unsigned b = __brev((unsigned)r) >> 22;
  return (int)(((b & 0x2AAu) >> 1) | ((b & 0x155u) << 1));
}

// ---------------- radix-4 twiddle tables in LDS ----------------
template <int NB4MAX>
__device__ inline void fill_tw(float2* TW, int tid, int T) {
#pragma unroll
  for (int sz = 1; sz <= NB4MAX; sz <<= 2) {
    int base = (sz - 1) / 3;
    for (int k = tid; k < sz; k += T) {
      float ang = (PI_F * 0.5f) * (float)k / (float)sz;
      float s1, c1;
      twiddle(ang, &s1, &c1);
      float2 w1 = make_float2(c1, s1);
      float2 w2 = cmul(w1, w1);
      float2 w3 = cmul(w2, w1);
      int e = (base + k) * 3;
      TW[e] = w1; TW[e + 1] = w2; TW[e + 2] = w3;
    }
  }
}

template <int SIGN>
__device__ inline void ldtw(const float2* __restrict__ TW, int sz, int k,
                            float2* w1, float2* w2, float2* w3) {
  int e = ((sz - 1) / 3 + k) * 3;
  float2 a = TW[e], b = TW[e + 1], c = TW[e + 2];
  if (SIGN < 0) { a.y = -a.y; b.y = -b.y; c.y = -c.y; }
  *w1 = a; *w2 = b; *w3 = c;
}

// ---------------- fully-unrolled 16-pt FFT in registers (natural in/out) ----------------
template <int SIGN>
__device__ inline void fft16_reg(float2* v) {
  const float sg = (float)SIGN;
  const float C1 = 0.9238795325112867f, S1 = 0.3826834323650898f, R = 0.7071067811865476f;
  float2 g[16];
#pragma unroll
  for (int a0 = 0; a0 < 4; ++a0) {
    float2 x0 = v[a0], x1 = v[a0 + 4], x2 = v[a0 + 8], x3 = v[a0 + 12];
    float2 t0 = x0 + x2;
    float2 t1 = x0 - x2;
    float2 t2 = x1 + x3;
    float2 t3 = x1 - x3;
    float2 j3 = cj<SIGN>(t3);
    g[a0 * 4 + 0] = t0 + t2;
    g[a0 * 4 + 1] = t1 + j3;
    g[a0 * 4 + 2] = t0 - t2;
    g[a0 * 4 + 3] = t1 - j3;
  }
  g[5]  = cmulc(g[5],  C1, sg * S1);
  g[6]  = cmulc(g[6],  R,  sg * R);
  g[7]  = cmulc(g[7],  S1, sg * C1);
  g[9]  = cmulc(g[9],  R,  sg * R);
  g[10] = cj<SIGN>(g[10]);
  g[11] = cmulc(g[11], -R, sg * R);
  g[13] = cmulc(g[13], S1, sg * C1);
  g[14] = cmulc(g[14], -R, sg * R);
  g[15] = cmulc(g[15], -C1, -sg * S1);
#pragma unroll
  for (int k0 = 0; k0 < 4; ++k0) {
    float2 x0 = g[k0], x1 = g[4 + k0], x2 = g[8 + k0], x3 = g[12 + k0];
    float2 t0 = x0 + x2;
    float2 t1 = x0 - x2;
    float2 t2 = x1 + x3;
    float2 t3 = x1 - x3;
    float2 j3 = cj<SIGN>(t3);
    v[k0]      = t0 + t2;
    v[k0 + 4]  = t1 + j3;
    v[k0 + 8]  = t0 - t2;
    v[k0 + 12] = t1 - j3;
  }
}

// ---------------- Stockham radix-4 FFT in LDS (row passes) ----------------
template <int N, int T, int SIGN>
__device__ inline float2* fft4_lds(float2* bufA, float2* bufB, int tid,
                                   const float2* __restrict__ TW) {
  const int NB4 = N / 4;
  const int BPT = NB4 / T;
  const int STAGES = (N == 1024) ? 5 : 4;
  float2* src = bufA;
  float2* dst = bufB;
  for (int s = 0; s < STAGES; ++s) {
    const int m = 1 << (2 * s);
    const int l = NB4 >> (2 * s);
    __syncthreads();
#pragma unroll
    for (int u = 0; u < BPT; ++u) {
      int bf = tid + u * T;
      int k = bf & (m - 1);
      int j = bf >> (2 * s);
      float2 x0 = src[bf];
      float2 x1 = src[bf + NB4];
      float2 x2 = src[bf + 2 * NB4];
      float2 x3 = src[bf + 3 * NB4];
      float2 t0 = x0 + x2;
      float2 t1 = x0 - x2;
      float2 t2 = x1 + x3;
      float2 t3 = x1 - x3;
      float2 j3 = cj<SIGN>(t3);
      float2 y0 = t0 + t2;
      float2 y1 = t1 + j3;
      float2 y2 = t0 - t2;
      float2 y3 = t1 - j3;
      float2 w1, w2, w3;
      ldtw<SIGN>(TW, l, j, &w1, &w2, &w3);
      int o = ((bf - k) << 2) + k;
      dst[o] = y0;
      dst[o + m] = cmul(y1, w1);
      dst[o + 2 * m] = cmul(y2, w2);
      dst[o + 3 * m] = cmul(y3, w3);
    }
    float2* tmp = src; src = dst; dst = tmp;
  }
  __syncthreads();
  return src;
}

// ---------------- in-place multi-column radix-4 FFTs (1024-pt column passes) ----------------
template <int N, int CW, int T, int SIGN>
__device__ inline void dif4_mc(float2* A, int tid, const float2* __restrict__ TW) {
  const int NB4 = N / 4;
  const int LOG4 = (N == 1024) ? 5 : 4;
  const int ITER = (NB4 * CW) / T;
  const int BSTR = T / CW;
  int c = tid & (CW - 1);
  int bb = tid / CW;
  for (int s = 0; s < LOG4; ++s) {
    int q = NB4 >> (2 * s);
    __syncthreads();
#pragma unroll
    for (int u = 0; u < ITER; ++u) {
      int bf = bb + BSTR * u;
      int j = bf & (q - 1);
      int i0 = ((bf - j) << 2) + j;
      float2 x0 = A[(i0) * CW + c];
      float2 x1 = A[(i0 + q) * CW + c];
      float2 x2 = A[(i0 + 2 * q) * CW + c];
      float2 x3 = A[(i0 + 3 * q) * CW + c];
      float2 t0 = x0 + x2;
      float2 t1 = x0 - x2;
      float2 t2 = x1 + x3;
      float2 t3 = x1 - x3;
      float2 j3 = cj<SIGN>(t3);
      float2 y0 = t0 + t2;
      float2 y1 = t1 + j3;
      float2 y2 = t0 - t2;
      float2 y3 = t1 - j3;
      float2 w1, w2, w3;
      ldtw<SIGN>(TW, q, j, &w1, &w2, &w3);
      A[(i0) * CW + c] = y0;
      A[(i0 + q) * CW + c] = cmul(y1, w1);
      A[(i0 + 2 * q) * CW + c] = cmul(y2, w2);
      A[(i0 + 3 * q) * CW + c] = cmul(y3, w3);
    }
  }
  __syncthreads();
}

template <int N, int CW, int T, int SIGN>
__device__ inline void dit4_mc(float2* A, int tid, const float2* __restrict__ TW) {
  const int NB4 = N / 4;
  const int LOG4 = (N == 1024) ? 5 : 4;
  const int ITER = (NB4 * CW) / T;
  const int BSTR = T / CW;
  int c = tid & (CW - 1);
  int bb = tid / CW;
  for (int s = 0; s < LOG4; ++s) {
    int m = 1 << (2 * s);
    __syncthreads();
#pragma unroll
    for (int u = 0; u < ITER; ++u) {
      int bf = bb + BSTR * u;
      int k = bf & (m - 1);
      int i0 = ((bf - k) << 2) + k;
      float2 w1, w2, w3;
      ldtw<SIGN>(TW, m, k, &w1, &w2, &w3);
      float2 x0 = A[(i0) * CW + c];
      float2 x1 = cmul(A[(i0 + m) * CW + c], w1);
      float2 x2 = cmul(A[(i0 + 2 * m) * CW + c], w2);
      float2 x3 = cmul(A[(i0 + 3 * m) * CW + c], w3);
      float2 t0 = x0 + x2;
      float2 t1 = x0 - x2;
      float2 t2 = x1 + x3;
      float2 t3 = x1 - x3;
      float2 j3 = cj<SIGN>(t3);
      A[(i0) * CW + c] = t0 + t2;
      A[(i0 + m) * CW + c] = t1 + j3;
      A[(i0 + 2 * m) * CW + c] = t0 - t2;
      A[(i0 + 3 * m) * CW + c] = t1 - j3;
    }
  }
  __syncthreads();
}

// ---------------- 1024-point row passes ----------------

__global__ __launch_bounds__(256) void k_fft_rows_big(
    const float* __restrict__ re, const float* __restrict__ im,
    half2v* __restrict__ zf) {
  __shared__ float2 A[1024], Bb[1024];
  __shared__ float2 TW[341 * 3];
  long base = (long)blockIdx.x * 1024;
  int tid = threadIdx.x;
  fill_tw<256>(TW, tid, 256);
#pragma unroll
  for (int k = 0; k < 4; ++k) {
    int q = tid + k * 256;
    A[q] = make_float2(re[base + q], im[base + q]);
  }
  float2* res = fft4_lds<1024, 256, -1>(A, Bb, tid, TW);
#pragma unroll
  for (int k = 0; k < 4; ++k) {
    int q = tid + k * 256;
    zf[base + ((q + 512) & 1023)] = f2h(res[q]);
  }
}

// row IFFT of U fused with the final combine
__global__ __launch_bounds__(256) void k_ifft_rows_combine(
    const float2* __restrict__ U, const float* __restrict__ Ia,
    const float* __restrict__ Icr, const float* __restrict__ Ici,
    const float* __restrict__ lamb, const float* __restrict__ eta1,
    float* __restrict__ out, long out_elems) {
  __shared__ float2 A[1024], Bb[1024];
  __shared__ float2 TW[341 * 3];
  long base = (long)blockIdx.x * 1024;
  int tid = threadIdx.x;
  fill_tw<256>(TW, tid, 256);
#pragma unroll
  for (int k = 0; k < 4; ++k) {
    int q = tid + k * 256;
    A[q] = U[base + ((q + 512) & 1023)];
  }
  float2* res = fft4_lds<1024, 256, 1>(A, Bb, tid, TW);
  const float sc = 1.0f / 1024.0f;
  const long NTOT = 4L * 1024 * 1024;
  float e1 = eta1[0], lm = lamb[0];
  float c1 = 100.0f * e1 * lm;
  float c2 = 10.0f * e1;
#pragma unroll
  for (int k = 0; k < 4; ++k) {
    int q = tid + k * 256;
    long i = base + q;
    float2 w = cscale(res[q], sc);
    float cr = Icr[i], ci = Ici[i], a = Ia[i];
    float mag = sqrtf(cr * cr + ci * ci);
    float t = a / (mag + EPSF);
    float rx = cr * (1.0f - c1) + c1 * cr * t - c2 * w.x;
    float ry = ci * (1.0f - c1) + c1 * ci * t - c2 * w.y;
    if (i < out_elems) out[i] = sqrtf(rx * rx + ry * ry);
    if (NTOT + i < out_elems) out[NTOT + i] = rx;
    if (2 * NTOT + i < out_elems) out[2 * NTOT + i] = ry;
  }
}

// ---------------- 1024-point column passes (zf fp16; LDS compute fp32) ----------------

__global__ __launch_bounds__(256) void k_fft_cols_mc(half2v* __restrict__ zf) {
  __shared__ float2 A[8192];
  __shared__ float2 TW[341 * 3];
  int b = blockIdx.x >> 7;
  int c0 = (blockIdx.x & 127) * 8;
  long base = (long)b * 1048576 + c0;
  int tid = threadIdx.x;
  fill_tw<256>(TW, tid, 256);
#pragma unroll
  for (int u = 0; u < 32; ++u) {
    int v = tid + 256 * u;
    int r = v >> 3, c = v & 7;
    A[v] = h2f(zf[base + (long)r * 1024 + c]);
  }
  dif4_mc<1024, 8, 256, -1>(A, tid, TW);
#pragma unroll
  for (int u = 0; u < 32; ++u) {
    int v = tid + 256 * u;
    int r = v >> 3, c = v & 7;
    int i = rev4_10(r);
    zf[base + (long)((i + 512) & 1023) * 1024 + c] = f2h(A[v]);
  }
}

__global__ __launch_bounds__(256) void k_ifft_cols_mc(float2* __restrict__ U) {
  __shared__ float2 A[8192];
  __shared__ float2 TW[341 * 3];
  int b = blockIdx.x >> 7;
  int c0 = (blockIdx.x & 127) * 8;
  long base = (long)b * 1048576 + c0;
  int tid = threadIdx.x;
  fill_tw<256>(TW, tid, 256);
#pragma unroll
  for (int u = 0; u < 32; ++u) {
    int v = tid + 256 * u;
    int r = v >> 3, c = v & 7;
    int i = rev4_10(r);
    A[v] = U[base + (long)((i + 512) & 1023) * 1024 + c];
  }
  dit4_mc<1024, 8, 256, 1>(A, tid, TW);
  const float sc = 1.0f / 1024.0f;
#pragma unroll
  for (int u = 0; u < 32; ++u) {
    int v = tid + 256 * u;
    int r = v >> 3, c = v & 7;
    U[base + (long)r * 1024 + c] = cscale(A[v], sc);
  }
}

// ---------------- 256-point patch passes (P stored as fp16 complex) ----------------

__global__ __launch_bounds__(256) void k_patch_gather_irows(
    const half2v* __restrict__ zf, const int* __restrict__ masks,
    const float* __restrict__ ctf, half2v* __restrict__ P, int g0) {
  __shared__ float2 A[1024], Bb[1024];
  __shared__ float2 TW[85 * 3];
  int idx = blockIdx.x;  // li*64 + p4
  int li = idx >> 6;
  int sub = threadIdx.x >> 6;
  int p = ((idx & 63) << 2) + sub;
  int t = threadIdx.x & 63;
  int g = g0 + li;
  int l = g & 63, b = g >> 6;
  int br = masks[2 * l] - 1, bc = masks[2 * l + 1] - 1;
  int sp = (p + 128) & 255;
  long zbase = (long)b * (1024 * 1024) + (long)(br + sp) * 1024 + bc;
  const float* crow = ctf + sp * 256;
  float2* Ar = A + sub * 256;
  float2* Br = Bb + sub * 256;
  fill_tw<64>(TW, threadIdx.x, 256);
#pragma unroll
  for (int k = 0; k < 4; ++k) {
    int q = t + k * 64;
    int sq = (q + 128) & 255;
    float cv = crow[sq];
    float2 v = h2f(zf[zbase + sq]);
    Ar[q] = cscale(v, cv);
  }
  float2* res = fft4_lds<256, 64, 1>(Ar, Br, t, TW);
  const float sc = 1.0f / 256.0f;
  long pbase = ((long)li * 256 + p) * 256;
#pragma unroll
  for (int k = 0; k < 4; ++k) {
    int q = t + k * 64;
    P[pbase + q] = f2h(cscale(res[q], sc));
  }
}

// Register-resident 16x16 column IFFT -> phase replace -> column FFT.
// (round-10 shape: 256 threads / 16-column slab, fp16 TZ, best measured 65.7 us)
__global__ __launch_bounds__(256) void k_patch_cz_reg(
    half2v* __restrict__ P, const float* __restrict__ Y, int g0) {
  __shared__ half2v TZ[4352];   // 16x16x(16 pad 17), fp16
  __shared__ float2 W[256];     // W[m] = exp(+2pi i m/256)
  int li = blockIdx.x >> 4;
  int q0 = (blockIdx.x & 15) * 16;
  int g = g0 + li;
  int tid = threadIdx.x;
  int lo = tid & 15;
  int hi = tid >> 4;
  // prefetch Y (hides the load latency under phases 1-2)
  const float* Yg = Y + (long)g * 65536 + q0 + lo;
  float sY[16];
#pragma unroll
  for (int d = 0; d < 16; ++d) sY[d] = Yg[(long)(hi + 16 * d) * 256];
  {
    float ang = (2.0f * PI_F / 256.0f) * (float)tid;
    float sn, cs;
    twiddle(ang, &sn, &cs);
    W[tid] = make_float2(cs, sn);
  }
  long pcol = (long)li * 65536 + q0 + lo;
  float2 v[16];
#pragma unroll
  for (int a = 0; a < 16; ++a) v[a] = h2f(P[pcol + (long)(16 * a + hi) * 256]);
  fft16_reg<1>(v);
  __syncthreads();
#pragma unroll
  for (int c = 1; c < 16; ++c) v[c] = cmul(v[c], W[hi * c]);
#pragma unroll
  for (int c = 0; c < 16; ++c) TZ[(hi * 16 + c) * 17 + lo] = f2h(v[c]);
  __syncthreads();
#pragma unroll
  for (int b = 0; b < 16; ++b) v[b] = h2f(TZ[(b * 16 + hi) * 17 + lo]);
  fft16_reg<1>(v);
  const float sc = 1.0f / 256.0f;
#pragma unroll
  for (int d = 0; d < 16; ++d) {
    float2 bz = cscale(v[d], sc);
    float s = sqrtf(sY[d]);
    float m2 = bz.x * bz.x + bz.y * bz.y;
    float inv = (m2 > 0.0f) ? rsqrtf(m2) : 0.0f;
    float px = (m2 > 0.0f) ? bz.x * inv : 1.0f;
    float py = bz.y * inv;
    v[d] = make_float2(bz.x - s * px, bz.y - s * py);
  }
  fft16_reg<-1>(v);
#pragma unroll
  for (int e = 1; e < 16; ++e) {
    float2 w = W[hi * e];
    v[e] = cmul(v[e], make_float2(w.x, -w.y));
  }
  __syncthreads();
#pragma unroll
  for (int e = 0; e < 16; ++e) TZ[(hi * 16 + e) * 17 + lo] = f2h(v[e]);
  __syncthreads();
#pragma unroll
  for (int c = 0; c < 16; ++c) v[c] = h2f(TZ[(c * 16 + hi) * 17 + lo]);
  fft16_reg<-1>(v);
#pragma unroll
  for (int f = 0; f < 16; ++f) {
    int row = (hi + 16 * f + 128) & 255;
    P[(long)li * 65536 + (long)row * 256 + q0 + lo] = f2h(v[f]);
  }
}

// (fallback only) row-FFT patches in place
__global__ __launch_bounds__(256) void k_patch_rows_store(
    half2v* __restrict__ P, const float* __restrict__ ctf) {
  __shared__ float2 A[1024], Bb[1024];
  __shared__ float2 TW[85 * 3];
  int idx = blockIdx.x;
  int li = idx >> 6;
  int sub = threadIdx.x >> 6;
  int p = ((idx & 63) << 2) + sub;
  int t = threadIdx.x & 63;
  long pbase = ((long)li * 256 + p) * 256;
  float2* Ar = A + sub * 256;
  float2* Br = Bb + sub * 256;
  fill_tw<64>(TW, threadIdx.x, 256);
#pragma unroll
  for (int k = 0; k < 4; ++k) {
    int q = t + k * 64;
    Ar[q] = h2f(P[pbase + q]);
  }
  float2* res = fft4_lds<256, 64, -1>(Ar, Br, t, TW);
  const float sc = 1.0f / 64.0f;
  const float* crow = ctf + p * 256;
#pragma unroll
  for (int k = 0; k < 4; ++k) {
    int q = t + k * 64;
    int qp = (q + 128) & 255;
    float cv = crow[qp] * sc;
    P[pbase + qp] = f2h(cscale(res[q], cv));
  }
}

// FULL mode: fused row-FFT + gather-accumulate, register-resident 16x16 row FFTs.
// 16 rows per batch, 16 threads per row (reuses cz's verified forward-FFT math).
__global__ __launch_bounds__(256) void k_patch_accum_fft(
    const half2v* __restrict__ P, const int* __restrict__ masks,
    const float* __restrict__ ctf, float2* __restrict__ U) {
  __shared__ half2v TZ[4352];      // (slot*16+hi)*17 + c
  __shared__ half2v RES[16][257];  // padded: write banks spread
  __shared__ float2 W[256];
  __shared__ int cl_li[64], cl_dr[64], cl_bc[64];
  __shared__ int s_n;
  int r = blockIdx.x & 1023;
  int b = blockIdx.x >> 10;
  int tid = threadIdx.x;
  {
    float ang = (2.0f * PI_F / 256.0f) * (float)tid;
    float sn, cs;
    twiddle(ang, &sn, &cs);
    W[tid] = make_float2(cs, sn);
  }
  if (tid < 64) {
    int br = masks[2 * tid] - 1;
    int dr = r - br;
    bool cov = (unsigned)dr < 256u;
    unsigned long long m = __ballot(cov);  // wave 0 covers tids 0..63
    if (cov) {
      int slot = __popcll(m & ((1ull << tid) - 1ull));
      cl_li[slot] = tid;
      cl_dr[slot] = dr;
      cl_bc[slot] = masks[2 * tid + 1] - 1;
    }
    if (tid == 0) s_n = (int)__popcll(m);
  }
  __syncthreads();
  int n = s_n;
  int slot = tid >> 4;   // row slot within batch, 0..15
  int hi = tid & 15;     // FFT digit
  float2 acc[4];
#pragma unroll
  for (int k = 0; k < 4; ++k) acc[k] = make_float2(0.0f, 0.0f);
  const float sc = 1.0f / 64.0f;
  for (int s0 = 0; s0 < n; s0 += 16) {
    int s = s0 + slot;
    bool live = s < n;
    float2 v[16];
    if (live) {
      long pbase = (((long)b * 64 + cl_li[s]) * 256 + cl_dr[s]) * 256;
#pragma unroll
      for (int a = 0; a < 16; ++a) v[a] = h2f(P[pbase + 16 * a + hi]);
      fft16_reg<-1>(v);
#pragma unroll
      for (int e = 1; e < 16; ++e) {
        float2 w = W[hi * e];
        v[e] = cmul(v[e], make_float2(w.x, -w.y));
      }
    } else {
#pragma unroll
      for (int a = 0; a < 16; ++a) v[a] = make_float2(0.0f, 0.0f);
    }
#pragma unroll
    for (int e = 0; e < 16; ++e) TZ[(slot * 16 + hi) * 17 + e] = f2h(v[e]);
    __syncthreads();
#pragma unroll
    for (int c = 0; c < 16; ++c) v[c] = h2f(TZ[(slot * 16 + c) * 17 + hi]);
    fft16_reg<-1>(v);
    int dr2 = live ? cl_dr[s] : 0;
    const float* crow = ctf + dr2 * 256;
#pragma unroll
    for (int f = 0; f < 16; ++f) {
      int col = (hi + 16 * f + 128) & 255;
      float cv = crow[col] * sc;
      RES[slot][col] = f2h(cscale(v[f], cv));
    }
    __syncthreads();
    int mm = (n - s0) < 16 ? (n - s0) : 16;
    for (int ss = 0; ss < mm; ++ss) {
      int bc2 = cl_bc[s0 + ss];
#pragma unroll
      for (int k = 0; k < 4; ++k) {
        int dc = tid + 256 * k - bc2;
        if ((unsigned)dc < 256u) {
          acc[k] = acc[k] + h2f(RES[ss][dc]);
        }
      }
    }
    __syncthreads();
  }
  long ubase = (long)b * 1048576 + (long)r * 1024;
#pragma unroll
  for (int k = 0; k < 4; ++k) U[ubase + tid + 256 * k] = acc[k];
}

// (fallback only) plain gather-accumulate
__global__ __launch_bounds__(256) void k_patch_accum(
    const half2v* __restrict__ P, const int* __restrict__ masks,
    float2* __restrict__ U, int b_base, int l0, int nc, int accum, int g0) {
  __shared__ int sbr[64], sbc[64];
  int r = blockIdx.x & 1023;
  int b = b_base + (blockIdx.x >> 10);
  int tid = threadIdx.x;
  if (tid < nc) {
    sbr[tid] = masks[2 * (l0 + tid)] - 1;
    sbc[tid] = masks[2 * (l0 + tid) + 1] - 1;
  }
  __syncthreads();
  long ubase = (long)b * 1048576 + (long)r * 1024;
  long sbase = (long)(b * 64 + l0 - g0);
  float2 acc[4];
  if (accum) {
#pragma unroll
    for (int k = 0; k < 4; ++k) acc[k] = U[ubase + tid + 256 * k];
  } else {
#pragma unroll
    for (int k = 0; k < 4; ++k) acc[k] = make_float2(0.0f, 0.0f);
  }
  for (int li = 0; li < nc; ++li) {
    int dr = r - sbr[li];
    if ((unsigned)dr < 256u) {
      const half2v* prow = P + ((sbase + li) * 256 + dr) * 256;
      int bc = sbc[li];
#pragma unroll
      for (int k = 0; k < 4; ++k) {
        int dc = tid + 256 * k - bc;
        if ((unsigned)dc < 256u) {
          acc[k] = acc[k] + h2f(prow[dc]);
        }
      }
    }
  }
#pragma unroll
  for (int k = 0; k < 4; ++k) U[ubase + tid + 256 * k] = acc[k];
}

extern "C" void kernel_launch(void* const* d_in, const int* in_sizes, int n_in,
                              void* d_out, int out_size, void* d_ws, size_t ws_size,
                              hipStream_t stream) {
  (void)in_sizes; (void)n_in;
  const float* Ia   = (const float*)d_in[0];
  const float* Icr  = (const float*)d_in[1];
  const float* Ici  = (const float*)d_in[2];
  const float* Y    = (const float*)d_in[3];
  const int*   Masks = (const int*)d_in[4];
  const float* CTF  = (const float*)d_in[5];
  const float* lamb = (const float*)d_in[6];
  const float* eta1 = (const float*)d_in[7];
  float* out = (float*)d_out;

  const size_t MB32 = 32ull * 1024 * 1024;
  const size_t MB16 = 16ull * 1024 * 1024;
  const size_t PATCH_BYTES = 256 * 256 * sizeof(half2v);  // 256 KiB (fp16)
  const size_t P_FULL = 256ull * PATCH_BYTES;             // 64 MiB

  char* wsb = (char*)d_ws;

  // ---------- FULL mode: all 4 batches in one patch pipeline ----------
  if (ws_size >= MB32 + MB16 + P_FULL) {
    float2* U  = (float2*)wsb;
    half2v* zf = (half2v*)(wsb + MB32);
    half2v* P  = (half2v*)(wsb + MB32 + MB16);

    k_fft_rows_big<<<4096, 256, 0, stream>>>(Icr, Ici, zf);
    k_fft_cols_mc<<<512, 256, 0, stream>>>(zf);

    k_patch_gather_irows<<<256 * 64, 256, 0, stream>>>(zf, Masks, CTF, P, 0);
    k_patch_cz_reg<<<256 * 16, 256, 0, stream>>>(P, Y, 0);
    k_patch_accum_fft<<<4096, 256, 0, stream>>>(P, Masks, CTF, U);

    k_ifft_cols_mc<<<512, 256, 0, stream>>>(U);
    k_ifft_rows_combine<<<4096, 256, 0, stream>>>(U, Ia, Icr, Ici, lamb, eta1, out,
                                                  (long)out_size);
    return;
  }

  // ---------- fallback: chunked pipeline ----------
  float2* U = (float2*)wsb;
  size_t used = MB32;
  if (used > ws_size) used = ws_size;

  half2v* zf;
  bool zf_in_ws = (ws_size >= MB32 + MB16 + PATCH_BYTES);
  bool zf_in_out = (!zf_in_ws) && ((size_t)out_size * sizeof(float) >= MB16);
  if (zf_in_ws) { zf = (half2v*)(wsb + used); used += MB16; }
  else if (zf_in_out) { zf = (half2v*)d_out; }
  else { zf = (half2v*)U; }

  size_t rem = (ws_size > used) ? (ws_size - used) : 0;
  long ncl = (long)(rem / PATCH_BYTES);
  int NC = (int)(ncl < 1 ? 1 : (ncl > 64 ? 64 : ncl));
  half2v* P = (half2v*)(wsb + ((rem >= PATCH_BYTES) ? used : 0));

  k_fft_rows_big<<<4096, 256, 0, stream>>>(Icr, Ici, zf);
  k_fft_cols_mc<<<512, 256, 0, stream>>>(zf);

  for (int b = 0; b < 4; ++b) {
    for (int l0 = 0; l0 < 64; l0 += NC) {
      int nc = (64 - l0) < NC ? (64 - l0) : NC;
      int g0 = b * 64 + l0;
      k_patch_gather_irows<<<nc * 64, 256, 0, stream>>>(zf, Masks, CTF, P, g0);
      k_patch_cz_reg<<<nc * 16, 256, 0, stream>>>(P, Y, g0);
      k_patch_rows_store<<<nc * 64, 256, 0, stream>>>(P, CTF);
      k_patch_accum<<<1024, 256, 0, stream>>>(P, Masks, U, b, l0, nc, l0 > 0 ? 1 : 0, g0);
    }
  }

  k_ifft_cols_mc<<<512, 256, 0, stream>>>(U);
  k_ifft_rows_combine<<<4096, 256, 0, stream>>>(U, Ia, Icr, Ici, lamb, eta1, out,
                                                (long)out_size);
}

// Round 14
// 336.904 us; speedup vs baseline: 1.1046x; 1.0609x over previous
//
#include <hip/hip_runtime.h>
#include <math.h>

#define PI_F 3.14159265358979323846f
#define EPSF 1e-6f

// ---- complex helpers written as float2 vector ops (clang emits v_pk_* on gfx950) ----
__device__ inline float2 cscale(float2 a, float s) { return make_float2(a.x * s, a.y * s); }
__device__ inline float2 cmul(float2 a, float2 b) {
  return b * a.x + make_float2(-b.y, b.x) * a.y;
}
__device__ inline float2 cmulc(float2 x, float cr, float ci) {
  return x * cr + make_float2(-x.y, x.x) * ci;
}
template <int SIGN>
__device__ inline float2 cj(float2 t) {  // SIGN * i * t
  return (SIGN > 0) ? make_float2(-t.y, t.x) : make_float2(t.y, -t.x);
}

// fp16 complex storage (P patch buffer, zf spectrum buffer, U image buffer, transposes)
typedef _Float16 half2v __attribute__((ext_vector_type(2)));
__device__ inline float2 h2f(half2v h) { return make_float2((float)h.x, (float)h.y); }
__device__ inline half2v f2h(float2 f) {
  half2v h; h.x = (_Float16)f.x; h.y = (_Float16)f.y; return h;
}

__device__ inline void twiddle(float ang, float* s, float* c) {
  __sincosf(ang, s, c);
}

// base-4 digit reversal (10-bit, N=1024 column passes)
__device__ inline int rev4_10(int r) {
  unsigned b = __brev((unsigned)r) >> 22;
  return (int)(((b & 0x2AAu) >> 1) | ((b & 0x155u) << 1));
}

// ---------------- radix-4 twiddle tables in LDS ----------------
template <int NB4MAX>
__device__ inline void fill_tw(float2* TW, int tid, int T) {
#pragma unroll
  for (int sz = 1; sz <= NB4MAX; sz <<= 2) {
    int base = (sz - 1) / 3;
    for (int k = tid; k < sz; k += T) {
      float ang = (PI_F * 0.5f) * (float)k / (float)sz;
      float s1, c1;
      twiddle(ang, &s1, &c1);
      float2 w1 = make_float2(c1, s1);
      float2 w2 = cmul(w1, w1);
      float2 w3 = cmul(w2, w1);
      int e = (base + k) * 3;
      TW[e] = w1; TW[e + 1] = w2; TW[e + 2] = w3;
    }
  }
}

template <int SIGN>
__device__ inline void ldtw(const float2* __restrict__ TW, int sz, int k,
                            float2* w1, float2* w2, float2* w3) {
  int e = ((sz - 1) / 3 + k) * 3;
  float2 a = TW[e], b = TW[e + 1], c = TW[e + 2];
  if (SIGN < 0) { a.y = -a.y; b.y = -b.y; c.y = -c.y; }
  *w1 = a; *w2 = b; *w3 = c;
}

// ---------------- fully-unrolled 16-pt FFT in registers (natural in/out) ----------------
template <int SIGN>
__device__ inline void fft16_reg(float2* v) {
  const float sg = (float)SIGN;
  const float C1 = 0.9238795325112867f, S1 = 0.3826834323650898f, R = 0.7071067811865476f;
  float2 g[16];
#pragma unroll
  for (int a0 = 0; a0 < 4; ++a0) {
    float2 x0 = v[a0], x1 = v[a0 + 4], x2 = v[a0 + 8], x3 = v[a0 + 12];
    float2 t0 = x0 + x2;
    float2 t1 = x0 - x2;
    float2 t2 = x1 + x3;
    float2 t3 = x1 - x3;
    float2 j3 = cj<SIGN>(t3);
    g[a0 * 4 + 0] = t0 + t2;
    g[a0 * 4 + 1] = t1 + j3;
    g[a0 * 4 + 2] = t0 - t2;
    g[a0 * 4 + 3] = t1 - j3;
  }
  g[5]  = cmulc(g[5],  C1, sg * S1);
  g[6]  = cmulc(g[6],  R,  sg * R);
  g[7]  = cmulc(g[7],  S1, sg * C1);
  g[9]  = cmulc(g[9],  R,  sg * R);
  g[10] = cj<SIGN>(g[10]);
  g[11] = cmulc(g[11], -R, sg * R);
  g[13] = cmulc(g[13], S1, sg * C1);
  g[14] = cmulc(g[14], -R, sg * R);
  g[15] = cmulc(g[15], -C1, -sg * S1);
#pragma unroll
  for (int k0 = 0; k0 < 4; ++k0) {
    float2 x0 = g[k0], x1 = g[4 + k0], x2 = g[8 + k0], x3 = g[12 + k0];
    float2 t0 = x0 + x2;
    float2 t1 = x0 - x2;
    float2 t2 = x1 + x3;
    float2 t3 = x1 - x3;
    float2 j3 = cj<SIGN>(t3);
    v[k0]      = t0 + t2;
    v[k0 + 4]  = t1 + j3;
    v[k0 + 8]  = t0 - t2;
    v[k0 + 12] = t1 - j3;
  }
}

// ---------------- Stockham radix-4 FFT in LDS (row passes) ----------------
template <int N, int T, int SIGN>
__device__ inline float2* fft4_lds(float2* bufA, float2* bufB, int tid,
                                   const float2* __restrict__ TW) {
  const int NB4 = N / 4;
  const int BPT = NB4 / T;
  const int STAGES = (N == 1024) ? 5 : 4;
  float2* src = bufA;
  float2* dst = bufB;
  for (int s = 0; s < STAGES; ++s) {
    const int m = 1 << (2 * s);
    const int l = NB4 >> (2 * s);
    __syncthreads();
#pragma unroll
    for (int u = 0; u < BPT; ++u) {
      int bf = tid + u * T;
      int k = bf & (m - 1);
      int j = bf >> (2 * s);
      float2 x0 = src[bf];
      float2 x1 = src[bf + NB4];
      float2 x2 = src[bf + 2 * NB4];
      float2 x3 = src[bf + 3 * NB4];
      float2 t0 = x0 + x2;
      float2 t1 = x0 - x2;
      float2 t2 = x1 + x3;
      float2 t3 = x1 - x3;
      float2 j3 = cj<SIGN>(t3);
      float2 y0 = t0 + t2;
      float2 y1 = t1 + j3;
      float2 y2 = t0 - t2;
      float2 y3 = t1 - j3;
      float2 w1, w2, w3;
      ldtw<SIGN>(TW, l, j, &w1, &w2, &w3);
      int o = ((bf - k) << 2) + k;
      dst[o] = y0;
      dst[o + m] = cmul(y1, w1);
      dst[o + 2 * m] = cmul(y2, w2);
      dst[o + 3 * m] = cmul(y3, w3);
    }
    float2* tmp = src; src = dst; dst = tmp;
  }
  __syncthreads();
  return src;
}

// ---------------- in-place multi-column radix-4 FFTs (1024-pt column passes) ----------------
template <int N, int CW, int T, int SIGN>
__device__ inline void dif4_mc(float2* A, int tid, const float2* __restrict__ TW) {
  const int NB4 = N / 4;
  const int LOG4 = (N == 1024) ? 5 : 4;
  const int ITER = (NB4 * CW) / T;
  const int BSTR = T / CW;
  int c = tid & (CW - 1);
  int bb = tid / CW;
  for (int s = 0; s < LOG4; ++s) {
    int q = NB4 >> (2 * s);
    __syncthreads();
#pragma unroll
    for (int u = 0; u < ITER; ++u) {
      int bf = bb + BSTR * u;
      int j = bf & (q - 1);
      int i0 = ((bf - j) << 2) + j;
      float2 x0 = A[(i0) * CW + c];
      float2 x1 = A[(i0 + q) * CW + c];
      float2 x2 = A[(i0 + 2 * q) * CW + c];
      float2 x3 = A[(i0 + 3 * q) * CW + c];
      float2 t0 = x0 + x2;
      float2 t1 = x0 - x2;
      float2 t2 = x1 + x3;
      float2 t3 = x1 - x3;
      float2 j3 = cj<SIGN>(t3);
      float2 y0 = t0 + t2;
      float2 y1 = t1 + j3;
      float2 y2 = t0 - t2;
      float2 y3 = t1 - j3;
      float2 w1, w2, w3;
      ldtw<SIGN>(TW, q, j, &w1, &w2, &w3);
      A[(i0) * CW + c] = y0;
      A[(i0 + q) * CW + c] = cmul(y1, w1);
      A[(i0 + 2 * q) * CW + c] = cmul(y2, w2);
      A[(i0 + 3 * q) * CW + c] = cmul(y3, w3);
    }
  }
  __syncthreads();
}

template <int N, int CW, int T, int SIGN>
__device__ inline void dit4_mc(float2* A, int tid, const float2* __restrict__ TW) {
  const int NB4 = N / 4;
  const int LOG4 = (N == 1024) ? 5 : 4;
  const int ITER = (NB4 * CW) / T;
  const int BSTR = T / CW;
  int c = tid & (CW - 1);
  int bb = tid / CW;
  for (int s = 0; s < LOG4; ++s) {
    int m = 1 << (2 * s);
    __syncthreads();
#pragma unroll
    for (int u = 0; u < ITER; ++u) {
      int bf = bb + BSTR * u;
      int k = bf & (m - 1);
      int i0 = ((bf - k) << 2) + k;
      float2 w1, w2, w3;
      ldtw<SIGN>(TW, m, k, &w1, &w2, &w3);
      float2 x0 = A[(i0) * CW + c];
      float2 x1 = cmul(A[(i0 + m) * CW + c], w1);
      float2 x2 = cmul(A[(i0 + 2 * m) * CW + c], w2);
      float2 x3 = cmul(A[(i0 + 3 * m) * CW + c], w3);
      float2 t0 = x0 + x2;
      float2 t1 = x0 - x2;
      float2 t2 = x1 + x3;
      float2 t3 = x1 - x3;
      float2 j3 = cj<SIGN>(t3);
      A[(i0) * CW + c] = t0 + t2;
      A[(i0 + m) * CW + c] = t1 + j3;
      A[(i0 + 2 * m) * CW + c] = t0 - t2;
      A[(i0 + 3 * m) * CW + c] = t1 - j3;
    }
  }
  __syncthreads();
}

// ---------------- 1024-point row passes ----------------

__global__ __launch_bounds__(256) void k_fft_rows_big(
    const float* __restrict__ re, const float* __restrict__ im,
    half2v* __restrict__ zf) {
  __shared__ float2 A[1024], Bb[1024];
  __shared__ float2 TW[341 * 3];
  long base = (long)blockIdx.x * 1024;
  int tid = threadIdx.x;
  fill_tw<256>(TW, tid, 256);
#pragma unroll
  for (int k = 0; k < 4; ++k) {
    int q = tid + k * 256;
    A[q] = make_float2(re[base + q], im[base + q]);
  }
  float2* res = fft4_lds<1024, 256, -1>(A, Bb, tid, TW);
#pragma unroll
  for (int k = 0; k < 4; ++k) {
    int q = tid + k * 256;
    zf[base + ((q + 512) & 1023)] = f2h(res[q]);
  }
}

// row IFFT of U fused with the final combine (U fp16)
__global__ __launch_bounds__(256) void k_ifft_rows_combine(
    const half2v* __restrict__ U, const float* __restrict__ Ia,
    const float* __restrict__ Icr, const float* __restrict__ Ici,
    const float* __restrict__ lamb, const float* __restrict__ eta1,
    float* __restrict__ out, long out_elems) {
  __shared__ float2 A[1024], Bb[1024];
  __shared__ float2 TW[341 * 3];
  long base = (long)blockIdx.x * 1024;
  int tid = threadIdx.x;
  fill_tw<256>(TW, tid, 256);
#pragma unroll
  for (int k = 0; k < 4; ++k) {
    int q = tid + k * 256;
    A[q] = h2f(U[base + ((q + 512) & 1023)]);
  }
  float2* res = fft4_lds<1024, 256, 1>(A, Bb, tid, TW);
  const float sc = 1.0f / 1024.0f;
  const long NTOT = 4L * 1024 * 1024;
  float e1 = eta1[0], lm = lamb[0];
  float c1 = 100.0f * e1 * lm;
  float c2 = 10.0f * e1;
#pragma unroll
  for (int k = 0; k < 4; ++k) {
    int q = tid + k * 256;
    long i = base + q;
    float2 w = cscale(res[q], sc);
    float cr = Icr[i], ci = Ici[i], a = Ia[i];
    float mag = sqrtf(cr * cr + ci * ci);
    float t = a / (mag + EPSF);
    float rx = cr * (1.0f - c1) + c1 * cr * t - c2 * w.x;
    float ry = ci * (1.0f - c1) + c1 * ci * t - c2 * w.y;
    if (i < out_elems) out[i] = sqrtf(rx * rx + ry * ry);
    if (NTOT + i < out_elems) out[NTOT + i] = rx;
    if (2 * NTOT + i < out_elems) out[2 * NTOT + i] = ry;
  }
}

// ---------------- 1024-point column passes (zf/U fp16; LDS compute fp32) ----------------

__global__ __launch_bounds__(256) void k_fft_cols_mc(half2v* __restrict__ zf) {
  __shared__ float2 A[8192];
  __shared__ float2 TW[341 * 3];
  int b = blockIdx.x >> 7;
  int c0 = (blockIdx.x & 127) * 8;
  long base = (long)b * 1048576 + c0;
  int tid = threadIdx.x;
  fill_tw<256>(TW, tid, 256);
#pragma unroll
  for (int u = 0; u < 32; ++u) {
    int v = tid + 256 * u;
    int r = v >> 3, c = v & 7;
    A[v] = h2f(zf[base + (long)r * 1024 + c]);
  }
  dif4_mc<1024, 8, 256, -1>(A, tid, TW);
#pragma unroll
  for (int u = 0; u < 32; ++u) {
    int v = tid + 256 * u;
    int r = v >> 3, c = v & 7;
    int i = rev4_10(r);
    zf[base + (long)((i + 512) & 1023) * 1024 + c] = f2h(A[v]);
  }
}

__global__ __launch_bounds__(256) void k_ifft_cols_mc(half2v* __restrict__ U) {
  __shared__ float2 A[8192];
  __shared__ float2 TW[341 * 3];
  int b = blockIdx.x >> 7;
  int c0 = (blockIdx.x & 127) * 8;
  long base = (long)b * 1048576 + c0;
  int tid = threadIdx.x;
  fill_tw<256>(TW, tid, 256);
#pragma unroll
  for (int u = 0; u < 32; ++u) {
    int v = tid + 256 * u;
    int r = v >> 3, c = v & 7;
    int i = rev4_10(r);
    A[v] = h2f(U[base + (long)((i + 512) & 1023) * 1024 + c]);
  }
  dit4_mc<1024, 8, 256, 1>(A, tid, TW);
  const float sc = 1.0f / 1024.0f;
#pragma unroll
  for (int u = 0; u < 32; ++u) {
    int v = tid + 256 * u;
    int r = v >> 3, c = v & 7;
    U[base + (long)r * 1024 + c] = f2h(cscale(A[v], sc));
  }
}

// ---------------- 256-point patch passes (P stored as fp16 complex) ----------------

// Register-resident 16x16 row IFFT gather: 16 rows per block, 16 threads per row.
// Same verified CT structure as cz phases 1-2 / accum's forward.
__global__ __launch_bounds__(256) void k_patch_gather_reg(
    const half2v* __restrict__ zf, const int* __restrict__ masks,
    const float* __restrict__ ctf, half2v* __restrict__ P, int g0) {
  __shared__ half2v TZ[4352];   // (slot*16+x)*17 + y
  __shared__ float2 W[256];     // W[m] = exp(+2pi i m/256)
  int li = blockIdx.x >> 4;
  int p0 = (blockIdx.x & 15) * 16;
  int g = g0 + li;
  int l = g & 63, b = g >> 6;
  int tid = threadIdx.x;
  {
    float ang = (2.0f * PI_F / 256.0f) * (float)tid;
    float sn, cs;
    twiddle(ang, &sn, &cs);
    W[tid] = make_float2(cs, sn);
  }
  int br = masks[2 * l] - 1, bc = masks[2 * l + 1] - 1;
  int slot = tid >> 4;          // row within group
  int hi = tid & 15;            // FFT digit (input residue)
  int p = p0 + slot;
  int sp = (p + 128) & 255;
  long zbase = (long)b * 1048576 + (long)(br + sp) * 1024 + bc;
  const float* crow = ctf + sp * 256;
  float2 v[16];
#pragma unroll
  for (int a = 0; a < 16; ++a) {
    int sq = (16 * a + hi + 128) & 255;
    v[a] = cscale(h2f(zf[zbase + sq]), crow[sq]);
  }
  fft16_reg<1>(v);
  __syncthreads();              // W ready
#pragma unroll
  for (int c = 1; c < 16; ++c) v[c] = cmul(v[c], W[hi * c]);
#pragma unroll
  for (int c = 0; c < 16; ++c) TZ[(slot * 16 + hi) * 17 + c] = f2h(v[c]);
  __syncthreads();
#pragma unroll
  for (int c = 0; c < 16; ++c) v[c] = h2f(TZ[(slot * 16 + c) * 17 + hi]);
  fft16_reg<1>(v);
  const float sc = 1.0f / 256.0f;
  long pbase = ((long)li * 256 + p) * 256;
#pragma unroll
  for (int d = 0; d < 16; ++d) {
    P[pbase + hi + 16 * d] = f2h(cscale(v[d], sc));
  }
}

// Register-resident 16x16 column IFFT -> phase replace -> column FFT.
__global__ __launch_bounds__(256) void k_patch_cz_reg(
    half2v* __restrict__ P, const float* __restrict__ Y, int g0) {
  __shared__ half2v TZ[4352];   // 16x16x(16 pad 17), fp16
  __shared__ float2 W[256];     // W[m] = exp(+2pi i m/256)
  int li = blockIdx.x >> 4;
  int q0 = (blockIdx.x & 15) * 16;
  int g = g0 + li;
  int tid = threadIdx.x;
  int lo = tid & 15;
  int hi = tid >> 4;
  // prefetch Y (hides the load latency under phases 1-2)
  const float* Yg = Y + (long)g * 65536 + q0 + lo;
  float sY[16];
#pragma unroll
  for (int d = 0; d < 16; ++d) sY[d] = Yg[(long)(hi + 16 * d) * 256];
  {
    float ang = (2.0f * PI_F / 256.0f) * (float)tid;
    float sn, cs;
    twiddle(ang, &sn, &cs);
    W[tid] = make_float2(cs, sn);
  }
  long pcol = (long)li * 65536 + q0 + lo;
  float2 v[16];
#pragma unroll
  for (int a = 0; a < 16; ++a) v[a] = h2f(P[pcol + (long)(16 * a + hi) * 256]);
  fft16_reg<1>(v);
  __syncthreads();
#pragma unroll
  for (int c = 1; c < 16; ++c) v[c] = cmul(v[c], W[hi * c]);
#pragma unroll
  for (int c = 0; c < 16; ++c) TZ[(hi * 16 + c) * 17 + lo] = f2h(v[c]);
  __syncthreads();
#pragma unroll
  for (int b = 0; b < 16; ++b) v[b] = h2f(TZ[(b * 16 + hi) * 17 + lo]);
  fft16_reg<1>(v);
  const float sc = 1.0f / 256.0f;
#pragma unroll
  for (int d = 0; d < 16; ++d) {
    float2 bz = cscale(v[d], sc);
    float s = sqrtf(sY[d]);
    float m2 = bz.x * bz.x + bz.y * bz.y;
    float inv = (m2 > 0.0f) ? rsqrtf(m2) : 0.0f;
    float px = (m2 > 0.0f) ? bz.x * inv : 1.0f;
    float py = bz.y * inv;
    v[d] = make_float2(bz.x - s * px, bz.y - s * py);
  }
  fft16_reg<-1>(v);
#pragma unroll
  for (int e = 1; e < 16; ++e) {
    float2 w = W[hi * e];
    v[e] = cmul(v[e], make_float2(w.x, -w.y));
  }
  __syncthreads();
#pragma unroll
  for (int e = 0; e < 16; ++e) TZ[(hi * 16 + e) * 17 + lo] = f2h(v[e]);
  __syncthreads();
#pragma unroll
  for (int c = 0; c < 16; ++c) v[c] = h2f(TZ[(c * 16 + hi) * 17 + lo]);
  fft16_reg<-1>(v);
#pragma unroll
  for (int f = 0; f < 16; ++f) {
    int row = (hi + 16 * f + 128) & 255;
    P[(long)li * 65536 + (long)row * 256 + q0 + lo] = f2h(v[f]);
  }
}

// FULL mode: fused row-FFT + gather-accumulate, register-resident 16x16 row FFTs.
__global__ __launch_bounds__(256) void k_patch_accum_fft(
    const half2v* __restrict__ P, const int* __restrict__ masks,
    const float* __restrict__ ctf, half2v* __restrict__ U) {
  __shared__ half2v TZ[4352];      // (slot*16+hi)*17 + c
  __shared__ half2v RES[16][257];  // padded: write banks spread
  __shared__ float2 W[256];
  __shared__ int cl_li[64], cl_dr[64], cl_bc[64];
  __shared__ int s_n;
  int r = blockIdx.x & 1023;
  int b = blockIdx.x >> 10;
  int tid = threadIdx.x;
  {
    float ang = (2.0f * PI_F / 256.0f) * (float)tid;
    float sn, cs;
    twiddle(ang, &sn, &cs);
    W[tid] = make_float2(cs, sn);
  }
  if (tid < 64) {
    int br = masks[2 * tid] - 1;
    int dr = r - br;
    bool cov = (unsigned)dr < 256u;
    unsigned long long m = __ballot(cov);  // wave 0 covers tids 0..63
    if (cov) {
      int slot = __popcll(m & ((1ull << tid) - 1ull));
      cl_li[slot] = tid;
      cl_dr[slot] = dr;
      cl_bc[slot] = masks[2 * tid + 1] - 1;
    }
    if (tid == 0) s_n = (int)__popcll(m);
  }
  __syncthreads();
  int n = s_n;
  int slot = tid >> 4;   // row slot within batch, 0..15
  int hi = tid & 15;     // FFT digit
  float2 acc[4];
#pragma unroll
  for (int k = 0; k < 4; ++k) acc[k] = make_float2(0.0f, 0.0f);
  const float sc = 1.0f / 64.0f;
  for (int s0 = 0; s0 < n; s0 += 16) {
    int s = s0 + slot;
    bool live = s < n;
    float2 v[16];
    if (live) {
      long pbase = (((long)b * 64 + cl_li[s]) * 256 + cl_dr[s]) * 256;
#pragma unroll
      for (int a = 0; a < 16; ++a) v[a] = h2f(P[pbase + 16 * a + hi]);
      fft16_reg<-1>(v);
#pragma unroll
      for (int e = 1; e < 16; ++e) {
        float2 w = W[hi * e];
        v[e] = cmul(v[e], make_float2(w.x, -w.y));
      }
    } else {
#pragma unroll
      for (int a = 0; a < 16; ++a) v[a] = make_float2(0.0f, 0.0f);
    }
#pragma unroll
    for (int e = 0; e < 16; ++e) TZ[(slot * 16 + hi) * 17 + e] = f2h(v[e]);
    __syncthreads();
#pragma unroll
    for (int c = 0; c < 16; ++c) v[c] = h2f(TZ[(slot * 16 + c) * 17 + hi]);
    fft16_reg<-1>(v);
    int dr2 = live ? cl_dr[s] : 0;
    const float* crow = ctf + dr2 * 256;
#pragma unroll
    for (int f = 0; f < 16; ++f) {
      int col = (hi + 16 * f + 128) & 255;
      float cv = crow[col] * sc;
      RES[slot][col] = f2h(cscale(v[f], cv));
    }
    __syncthreads();
    int mm = (n - s0) < 16 ? (n - s0) : 16;
    for (int ss = 0; ss < mm; ++ss) {
      int bc2 = cl_bc[s0 + ss];
#pragma unroll
      for (int k = 0; k < 4; ++k) {
        int dc = tid + 256 * k - bc2;
        if ((unsigned)dc < 256u) {
          acc[k] = acc[k] + h2f(RES[ss][dc]);
        }
      }
    }
    __syncthreads();
  }
  long ubase = (long)b * 1048576 + (long)r * 1024;
#pragma unroll
  for (int k = 0; k < 4; ++k) U[ubase + tid + 256 * k] = f2h(acc[k]);
}

// (fallback only) row-FFT patches in place
__global__ __launch_bounds__(256) void k_patch_rows_store(
    half2v* __restrict__ P, const float* __restrict__ ctf) {
  __shared__ float2 A[1024], Bb[1024];
  __shared__ float2 TW[85 * 3];
  int idx = blockIdx.x;
  int li = idx >> 6;
  int sub = threadIdx.x >> 6;
  int p = ((idx & 63) << 2) + sub;
  int t = threadIdx.x & 63;
  long pbase = ((long)li * 256 + p) * 256;
  float2* Ar = A + sub * 256;
  float2* Br = Bb + sub * 256;
  fill_tw<64>(TW, threadIdx.x, 256);
#pragma unroll
  for (int k = 0; k < 4; ++k) {
    int q = t + k * 64;
    Ar[q] = h2f(P[pbase + q]);
  }
  float2* res = fft4_lds<256, 64, -1>(Ar, Br, t, TW);
  const float sc = 1.0f / 64.0f;
  const float* crow = ctf + p * 256;
#pragma unroll
  for (int k = 0; k < 4; ++k) {
    int q = t + k * 64;
    int qp = (q + 128) & 255;
    float cv = crow[qp] * sc;
    P[pbase + qp] = f2h(cscale(res[q], cv));
  }
}

// (fallback only) plain gather-accumulate (U fp16)
__global__ __launch_bounds__(256) void k_patch_accum(
    const half2v* __restrict__ P, const int* __restrict__ masks,
    half2v* __restrict__ U, int b_base, int l0, int nc, int accum, int g0) {
  __shared__ int sbr[64], sbc[64];
  int r = blockIdx.x & 1023;
  int b = b_base + (blockIdx.x >> 10);
  int tid = threadIdx.x;
  if (tid < nc) {
    sbr[tid] = masks[2 * (l0 + tid)] - 1;
    sbc[tid] = masks[2 * (l0 + tid) + 1] - 1;
  }
  __syncthreads();
  long ubase = (long)b * 1048576 + (long)r * 1024;
  long sbase = (long)(b * 64 + l0 - g0);
  float2 acc[4];
  if (accum) {
#pragma unroll
    for (int k = 0; k < 4; ++k) acc[k] = h2f(U[ubase + tid + 256 * k]);
  } else {
#pragma unroll
    for (int k = 0; k < 4; ++k) acc[k] = make_float2(0.0f, 0.0f);
  }
  for (int li = 0; li < nc; ++li) {
    int dr = r - sbr[li];
    if ((unsigned)dr < 256u) {
      const half2v* prow = P + ((sbase + li) * 256 + dr) * 256;
      int bc = sbc[li];
#pragma unroll
      for (int k = 0; k < 4; ++k) {
        int dc = tid + 256 * k - bc;
        if ((unsigned)dc < 256u) {
          acc[k] = acc[k] + h2f(prow[dc]);
        }
      }
    }
  }
#pragma unroll
  for (int k = 0; k < 4; ++k) U[ubase + tid + 256 * k] = f2h(acc[k]);
}

extern "C" void kernel_launch(void* const* d_in, const int* in_sizes, int n_in,
                              void* d_out, int out_size, void* d_ws, size_t ws_size,
                              hipStream_t stream) {
  (void)in_sizes; (void)n_in;
  const float* Ia   = (const float*)d_in[0];
  const float* Icr  = (const float*)d_in[1];
  const float* Ici  = (const float*)d_in[2];
  const float* Y    = (const float*)d_in[3];
  const int*   Masks = (const int*)d_in[4];
  const float* CTF  = (const float*)d_in[5];
  const float* lamb = (const float*)d_in[6];
  const float* eta1 = (const float*)d_in[7];
  float* out = (float*)d_out;

  const size_t MB16 = 16ull * 1024 * 1024;
  const size_t PATCH_BYTES = 256 * 256 * sizeof(half2v);  // 256 KiB (fp16)
  const size_t P_FULL = 256ull * PATCH_BYTES;             // 64 MiB

  char* wsb = (char*)d_ws;

  // ---------- FULL mode: all 4 batches in one patch pipeline ----------
  if (ws_size >= MB16 + MB16 + P_FULL) {
    half2v* U  = (half2v*)wsb;
    half2v* zf = (half2v*)(wsb + MB16);
    half2v* P  = (half2v*)(wsb + 2 * MB16);

    k_fft_rows_big<<<4096, 256, 0, stream>>>(Icr, Ici, zf);
    k_fft_cols_mc<<<512, 256, 0, stream>>>(zf);

    k_patch_gather_reg<<<256 * 16, 256, 0, stream>>>(zf, Masks, CTF, P, 0);
    k_patch_cz_reg<<<256 * 16, 256, 0, stream>>>(P, Y, 0);
    k_patch_accum_fft<<<4096, 256, 0, stream>>>(P, Masks, CTF, U);

    k_ifft_cols_mc<<<512, 256, 0, stream>>>(U);
    k_ifft_rows_combine<<<4096, 256, 0, stream>>>(U, Ia, Icr, Ici, lamb, eta1, out,
                                                  (long)out_size);
    return;
  }

  // ---------- fallback: chunked pipeline ----------
  half2v* U = (half2v*)wsb;
  size_t used = MB16;
  if (used > ws_size) used = ws_size;

  half2v* zf;
  bool zf_in_ws = (ws_size >= MB16 + MB16 + PATCH_BYTES);
  bool zf_in_out = (!zf_in_ws) && ((size_t)out_size * sizeof(float) >= MB16);
  if (zf_in_ws) { zf = (half2v*)(wsb + used); used += MB16; }
  else if (zf_in_out) { zf = (half2v*)d_out; }
  else { zf = U; }

  size_t rem = (ws_size > used) ? (ws_size - used) : 0;
  long ncl = (long)(rem / PATCH_BYTES);
  int NC = (int)(ncl < 1 ? 1 : (ncl > 64 ? 64 : ncl));
  half2v* P = (half2v*)(wsb + ((rem >= PATCH_BYTES) ? used : 0));

  k_fft_rows_big<<<4096, 256, 0, stream>>>(Icr, Ici, zf);
  k_fft_cols_mc<<<512, 256, 0, stream>>>(zf);

  for (int b = 0; b < 4; ++b) {
    for (int l0 = 0; l0 < 64; l0 += NC) {
      int nc = (64 - l0) < NC ? (64 - l0) : NC;
      int g0 = b * 64 + l0;
      k_patch_gather_reg<<<nc * 16, 256, 0, stream>>>(zf, Masks, CTF, P, g0);
      k_patch_cz_reg<<<nc * 16, 256, 0, stream>>>(P, Y, g0);
      k_patch_rows_store<<<nc * 64, 256, 0, stream>>>(P, CTF);
      k_patch_accum<<<1024, 256, 0, stream>>>(P, Masks, U, b, l0, nc, l0 > 0 ? 1 : 0, g0);
    }
  }

  k_ifft_cols_mc<<<512, 256, 0, stream>>>(U);
  k_ifft_rows_combine<<<4096, 256, 0, stream>>>(U, Ia, Icr, Ici, lamb, eta1, out,
                                                (long)out_size);
}